// Round 1
// baseline (1205.130 us; speedup 1.0000x reference)
//
#include <hip/hip_runtime.h>
#include <hip/hip_bf16.h>
#include <math.h>

#define NEG_SLOPE 0.2f
#define N_LAYERS 4

static __device__ __forceinline__ float leaky(float v){ return v > 0.f ? v : NEG_SLOPE * v; }

// ---------------- CSR build (edge structure fixed across layers) ----------------

__global__ void fill_int_kernel(int* __restrict__ p, int v, int n){
  int i = blockIdx.x*blockDim.x + threadIdx.x;
  if(i < n) p[i] = v;
}

__global__ void hist_kernel(const int* __restrict__ dst, int E, int* __restrict__ deg){
  int e = blockIdx.x*blockDim.x + threadIdx.x;
  if(e < E) atomicAdd(&deg[dst[e]], 1);
}

// exclusive scan: offs[0]=0, offs[i+1]=sum(deg[0..i]). Single block, 256 threads.
__global__ void scan_kernel(const int* __restrict__ deg, int* __restrict__ offs, int N){
  __shared__ int sh[256];
  int t = threadIdx.x;
  int carry = 0;
  for(int base = 0; base < N; base += 256){
    int v = (base + t < N) ? deg[base + t] : 0;
    sh[t] = v; __syncthreads();
    for(int o = 1; o < 256; o <<= 1){
      int add = (t >= o) ? sh[t - o] : 0;
      __syncthreads();
      sh[t] += add;
      __syncthreads();
    }
    if(base + t < N) offs[base + t + 1] = carry + sh[t];
    carry += sh[255];
    __syncthreads();
  }
  if(t == 0) offs[0] = 0;
}

__global__ void scatter_kernel(const int* __restrict__ dst, int E,
                               const int* __restrict__ offs, int* __restrict__ cursor,
                               int* __restrict__ eids){
  int e = blockIdx.x*blockDim.x + threadIdx.x;
  if(e < E){
    int d = dst[e];
    int pos = offs[d] + atomicAdd(&cursor[d], 1);
    eids[pos] = e;
  }
}

// ---------------- fp32 tiled GEMM: C[M,N] = op(A)[M,K] @ B[K,N] (+ bias[N]) ----------------
// blockDim (BN/TN, BM/TM) = (16,16); TM=TN=4.

template<int BM, int BN, int BK, int TM, int TN, bool RELU_A, bool HAS_BIAS>
__global__ __launch_bounds__(256) void gemm_f32_kernel(
    const float* __restrict__ A, const float* __restrict__ B,
    const float* __restrict__ bias, float* __restrict__ C,
    int M, int N, int K){
  __shared__ float As[BK][BM + 4];   // stored transposed: As[k][m]
  __shared__ float Bs[BK][BN + 4];
  const int tx = threadIdx.x;
  const int ty = threadIdx.y;
  const int tid = ty * (BN / TN) + tx;
  const int row0 = blockIdx.y * BM;
  const int col0 = blockIdx.x * BN;
  float acc[TM][TN];
#pragma unroll
  for(int i = 0; i < TM; ++i)
#pragma unroll
    for(int j = 0; j < TN; ++j) acc[i][j] = 0.f;

  for(int k0 = 0; k0 < K; k0 += BK){
    constexpr int APT = (BM * BK / 4) / 256;
#pragma unroll
    for(int i = 0; i < APT; ++i){
      int f = tid + i * 256;
      int m = f / (BK / 4);
      int kq = f % (BK / 4);
      float4 v = make_float4(0.f, 0.f, 0.f, 0.f);
      if(row0 + m < M) v = *(const float4*)(A + (size_t)(row0 + m) * K + k0 + kq * 4);
      if(RELU_A){ v.x = fmaxf(v.x, 0.f); v.y = fmaxf(v.y, 0.f); v.z = fmaxf(v.z, 0.f); v.w = fmaxf(v.w, 0.f); }
      As[kq*4+0][m] = v.x; As[kq*4+1][m] = v.y; As[kq*4+2][m] = v.z; As[kq*4+3][m] = v.w;
    }
    constexpr int BPT = (BK * BN / 4) / 256;
#pragma unroll
    for(int i = 0; i < BPT; ++i){
      int f = tid + i * 256;
      int kk = f / (BN / 4);
      int nq = f % (BN / 4);
      *(float4*)&Bs[kk][nq * 4] = *(const float4*)(B + (size_t)(k0 + kk) * N + col0 + nq * 4);
    }
    __syncthreads();
#pragma unroll
    for(int k = 0; k < BK; ++k){
      float4 a4 = *(const float4*)&As[k][ty * TM];
      float4 b4 = *(const float4*)&Bs[k][tx * TN];
      float av[4] = {a4.x, a4.y, a4.z, a4.w};
      float bv[4] = {b4.x, b4.y, b4.z, b4.w};
#pragma unroll
      for(int i = 0; i < TM; ++i)
#pragma unroll
        for(int j = 0; j < TN; ++j) acc[i][j] += av[i] * bv[j];
    }
    __syncthreads();
  }
#pragma unroll
  for(int i = 0; i < TM; ++i){
    int r = row0 + ty * TM + i;
    if(r < M){
      float4 o = make_float4(acc[i][0], acc[i][1], acc[i][2], acc[i][3]);
      if(HAS_BIAS){
        const float* bp = bias + col0 + tx * TN;
        o.x += bp[0]; o.y += bp[1]; o.z += bp[2]; o.w += bp[3];
      }
      *(float4*)(C + (size_t)r * N + col0 + tx * TN) = o;
    }
  }
}

// ---------------- edge alpha: one wave per edge ----------------
// alphaE[e,h] = sum_c leaky(xl[src,h,c] + xr[dst,h,c] + rproj[rel,h,c]) * att[h,c]
// lane l, j in 0..3: float4 idx = j*64+l; head h = idx>>5 = 2j + (l>>5); c4 = 4*(l&31)

__global__ void edge_alpha_kernel(const float* __restrict__ xl, const float* __restrict__ xr,
                                  const float* __restrict__ rproj,
                                  const int* __restrict__ src, const int* __restrict__ dst,
                                  const int* __restrict__ rel,
                                  const float* __restrict__ att,
                                  float* __restrict__ alphaE, int E){
  int w = (int)((blockIdx.x * blockDim.x + threadIdx.x) >> 6);
  int lane = threadIdx.x & 63;
  if(w >= E) return;
  int s = src[w], d = dst[w], r = rel[w];
  const float4* xls = (const float4*)(xl + (size_t)s * 1024);
  const float4* xrd = (const float4*)(xr + (size_t)d * 1024);
  const float4* rp  = (const float4*)(rproj + (size_t)r * 1024);
  const float4* at4 = (const float4*)att;
  float res[4];
#pragma unroll
  for(int j = 0; j < 4; ++j){
    int idx = j * 64 + lane;
    int h = idx >> 5;
    float4 a = xls[idx], b = xrd[idx], c = rp[idx];
    float4 m = make_float4(leaky(a.x + b.x + c.x), leaky(a.y + b.y + c.y),
                           leaky(a.z + b.z + c.z), leaky(a.w + b.w + c.w));
    float4 av = at4[h * 32 + (lane & 31)];
    res[j] = m.x * av.x + m.y * av.y + m.z * av.z + m.w * av.w;
  }
#pragma unroll
  for(int o = 16; o >= 1; o >>= 1){
#pragma unroll
    for(int j = 0; j < 4; ++j) res[j] += __shfl_xor(res[j], o);
  }
  if((lane & 31) == 0){
    int hi = lane >> 5;
#pragma unroll
    for(int j = 0; j < 4; ++j) alphaE[(size_t)w * 8 + 2 * j + hi] = res[j];
  }
}

// ---------------- fused node kernel: one wave per node ----------------
// pass1: lproj acc (sum rproj[rel]/deg) + alpha max over incoming edges
// self alpha, softmax, pass2: weighted xl[src] sum, head-mean + bias

__global__ void node_fused_kernel(const float* __restrict__ xl, const float* __restrict__ xr,
                                  const float* __restrict__ rproj,
                                  const int* __restrict__ offs, const int* __restrict__ eids,
                                  const int* __restrict__ src, const int* __restrict__ rel,
                                  const float* __restrict__ alphaE,
                                  const float* __restrict__ att, const float* __restrict__ bias,
                                  float* __restrict__ xout, int N){
  int node = (int)((blockIdx.x * blockDim.x + threadIdx.x) >> 6);
  int lane = threadIdx.x & 63;
  if(node >= N) return;
  int beg = offs[node], end = offs[node + 1];
  float inv = 1.0f / fmaxf((float)(end - beg), 1.0f);
  const float4* xln = (const float4*)(xl + (size_t)node * 1024);
  const float4* xrn = (const float4*)(xr + (size_t)node * 1024);
  const float4* at4 = (const float4*)att;
  int hbase = lane >> 5;

  float4 lacc[4]; float amax[4];
#pragma unroll
  for(int j = 0; j < 4; ++j){ lacc[j] = make_float4(0.f,0.f,0.f,0.f); amax[j] = -INFINITY; }

  for(int p = beg; p < end; ++p){
    int e = eids[p];
    int r = rel[e];
    const float4* rp = (const float4*)(rproj + (size_t)r * 1024);
#pragma unroll
    for(int j = 0; j < 4; ++j){
      float4 v = rp[j * 64 + lane];
      lacc[j].x += v.x; lacc[j].y += v.y; lacc[j].z += v.z; lacc[j].w += v.w;
      amax[j] = fmaxf(amax[j], alphaE[(size_t)e * 8 + 2 * j + hbase]);
    }
  }

  float4 xl4[4];
  float aself[4];
#pragma unroll
  for(int j = 0; j < 4; ++j){
    int idx = j * 64 + lane;
    xl4[j] = xln[idx];
    float4 xr4 = xrn[idx];
    float4 m = make_float4(leaky(xl4[j].x + xr4.x + lacc[j].x * inv),
                           leaky(xl4[j].y + xr4.y + lacc[j].y * inv),
                           leaky(xl4[j].z + xr4.z + lacc[j].z * inv),
                           leaky(xl4[j].w + xr4.w + lacc[j].w * inv));
    float4 av = at4[(2 * j + hbase) * 32 + (lane & 31)];
    aself[j] = m.x * av.x + m.y * av.y + m.z * av.z + m.w * av.w;
  }
#pragma unroll
  for(int o = 16; o >= 1; o >>= 1){
#pragma unroll
    for(int j = 0; j < 4; ++j) aself[j] += __shfl_xor(aself[j], o);
  }

  float denom[4]; float4 num[4];
#pragma unroll
  for(int j = 0; j < 4; ++j){
    amax[j] = fmaxf(amax[j], aself[j]);
    float ws = expf(aself[j] - amax[j]);
    denom[j] = ws;
    num[j] = make_float4(xl4[j].x * ws, xl4[j].y * ws, xl4[j].z * ws, xl4[j].w * ws);
  }

  for(int p = beg; p < end; ++p){
    int e = eids[p];
    int s = src[e];
    const float4* xs = (const float4*)(xl + (size_t)s * 1024);
#pragma unroll
    for(int j = 0; j < 4; ++j){
      float w = expf(alphaE[(size_t)e * 8 + 2 * j + hbase] - amax[j]);
      denom[j] += w;
      float4 v = xs[j * 64 + lane];
      num[j].x += v.x * w; num[j].y += v.y * w; num[j].z += v.z * w; num[j].w += v.w * w;
    }
  }

  float4 sum = make_float4(0.f,0.f,0.f,0.f);
#pragma unroll
  for(int j = 0; j < 4; ++j){
    float dinv = 1.0f / denom[j];
    sum.x += num[j].x * dinv; sum.y += num[j].y * dinv;
    sum.z += num[j].z * dinv; sum.w += num[j].w * dinv;
  }
  sum.x += __shfl_xor(sum.x, 32);
  sum.y += __shfl_xor(sum.y, 32);
  sum.z += __shfl_xor(sum.z, 32);
  sum.w += __shfl_xor(sum.w, 32);

  if(lane < 32){
    float4 b4 = ((const float4*)bias)[lane];
    float4 o = make_float4(sum.x * 0.125f + b4.x, sum.y * 0.125f + b4.y,
                           sum.z * 0.125f + b4.z, sum.w * 0.125f + b4.w);
    ((float4*)(xout + (size_t)node * 128))[lane] = o;
  }
}

// ---------------- launch ----------------

extern "C" void kernel_launch(void* const* d_in, const int* in_sizes, int n_in,
                              void* d_out, int out_size, void* d_ws, size_t ws_size,
                              hipStream_t stream){
  const float* x0   = (const float*)d_in[0];
  const int*   ei   = (const int*)d_in[1];
  const float* rel0 = (const float*)d_in[2];
  const int*   ridx = (const int*)d_in[3];
  const float* Wl   = (const float*)d_in[4];
  const float* bl   = (const float*)d_in[5];
  const float* Wr   = (const float*)d_in[6];
  const float* br   = (const float*)d_in[7];
  const float* We   = (const float*)d_in[8];
  const float* att  = (const float*)d_in[9];
  const float* bias = (const float*)d_in[10];
  const float* Wb   = (const float*)d_in[11];
  const float* bb   = (const float*)d_in[12];

  const int D = 128, HC = 1024;
  const int N = in_sizes[0] / D;
  const int E = in_sizes[1] / 2;
  const int R = in_sizes[2] / D;

  const int* src = ei;
  const int* dst = ei + E;

  char* ws = (char*)d_ws;
  size_t off = 0;
  auto alloc = [&](size_t bytes) -> void* {
    void* p = ws + off;
    off += (bytes + 255) & ~(size_t)255;
    return p;
  };
  float* xl     = (float*)alloc((size_t)N * HC * 4);
  float* xr     = (float*)alloc((size_t)N * HC * 4);
  float* rproj  = (float*)alloc((size_t)R * HC * 4);
  float* alphaE = (float*)alloc((size_t)E * 8 * 4);
  float* xbufA  = (float*)alloc((size_t)N * D * 4);
  float* xbufB  = (float*)alloc((size_t)N * D * 4);
  float* rbufA  = (float*)alloc((size_t)R * D * 4);
  float* rbufB  = (float*)alloc((size_t)R * D * 4);
  int* deg    = (int*)alloc((size_t)N * 4);
  int* offs   = (int*)alloc((size_t)(N + 1) * 4);
  int* cursor = (int*)alloc((size_t)N * 4);
  int* eids   = (int*)alloc((size_t)E * 4);
  float* xbuf[2] = {xbufA, xbufB};
  float* rbuf[2] = {rbufA, rbufB};

  float* out_x = (float*)d_out;
  float* out_r = (float*)d_out + (size_t)N * D;

  // CSR build (once; edge structure is layer-invariant)
  fill_int_kernel<<<(N + 255) / 256, 256, 0, stream>>>(deg, 0, N);
  fill_int_kernel<<<(N + 255) / 256, 256, 0, stream>>>(cursor, 0, N);
  hist_kernel<<<(E + 255) / 256, 256, 0, stream>>>(dst, E, deg);
  scan_kernel<<<1, 256, 0, stream>>>(deg, offs, N);
  scatter_kernel<<<(E + 255) / 256, 256, 0, stream>>>(dst, E, offs, cursor, eids);

  dim3 blk(16, 16);
  for(int l = 0; l < N_LAYERS; ++l){
    const float* xin = (l == 0) ? x0   : xbuf[(l + 1) & 1];
    float*       xo  = (l == N_LAYERS - 1) ? out_x : xbuf[l & 1];
    const float* rin = (l == 0) ? rel0 : rbuf[(l + 1) & 1];
    float*       ro  = (l == N_LAYERS - 1) ? out_r : rbuf[l & 1];
    const float* Wl_l  = Wl + (size_t)l * D * HC;
    const float* bl_l  = bl + (size_t)l * HC;
    const float* Wr_l  = Wr + (size_t)l * D * HC;
    const float* br_l  = br + (size_t)l * HC;
    const float* We_l  = We + (size_t)l * D * HC;
    const float* att_l = att + (size_t)l * 8 * 128;
    const float* bias_l= bias + (size_t)l * D;
    const float* Wb_l  = Wb + (size_t)l * HC * D;
    const float* bb_l  = bb + (size_t)l * D;

    // rproj = relations @ We  (no bias) — the eproj trick: project R rows once
    gemm_f32_kernel<64,64,32,4,4,false,false><<<dim3(HC/64, (R+63)/64), blk, 0, stream>>>(
        rin, We_l, nullptr, rproj, R, HC, D);
    // xl = x @ Wl + bl ; xr = x @ Wr + br
    gemm_f32_kernel<64,64,32,4,4,false,true><<<dim3(HC/64, (N+63)/64), blk, 0, stream>>>(
        xin, Wl_l, bl_l, xl, N, HC, D);
    gemm_f32_kernel<64,64,32,4,4,false,true><<<dim3(HC/64, (N+63)/64), blk, 0, stream>>>(
        xin, Wr_l, br_l, xr, N, HC, D);
    // per-edge attention logits
    edge_alpha_kernel<<<(E * 64 + 255) / 256, 256, 0, stream>>>(
        xl, xr, rproj, src, dst, ridx, att_l, alphaE, E);
    // fused: self-loop proj (CSR mean of rproj), self alpha, softmax, aggregate, head-mean+bias
    node_fused_kernel<<<(N * 64 + 255) / 256, 256, 0, stream>>>(
        xl, xr, rproj, offs, eids, src, ridx, alphaE, att_l, bias_l, xo, N);
    // relation update: relu(rproj) @ Wb + bb
    gemm_f32_kernel<64,64,32,4,4,true,true><<<dim3(D/64, (R+63)/64), blk, 0, stream>>>(
        rproj, Wb_l, bb_l, ro, R, D, HC);
  }
}

// Round 2
// 1154.890 us; speedup vs baseline: 1.0435x; 1.0435x over previous
//
#include <hip/hip_runtime.h>
#include <hip/hip_bf16.h>
#include <math.h>

#define NEG_SLOPE 0.2f
#define N_LAYERS 4

typedef __bf16 bf16_t;
typedef __attribute__((ext_vector_type(8))) __bf16 bf16x8;
typedef __attribute__((ext_vector_type(4))) __bf16 bf16x4;
typedef __attribute__((ext_vector_type(4))) float f32x4;

static __device__ __forceinline__ float leaky(float v){ return v > 0.f ? v : NEG_SLOPE * v; }

// ---------------- CSR build (edge structure fixed across layers) ----------------

__global__ void fill_int_kernel(int* __restrict__ p, int v, int n){
  int i = blockIdx.x*blockDim.x + threadIdx.x;
  if(i < n) p[i] = v;
}

__global__ void hist_kernel(const int* __restrict__ dst, int E, int* __restrict__ deg){
  int e = blockIdx.x*blockDim.x + threadIdx.x;
  if(e < E) atomicAdd(&deg[dst[e]], 1);
}

// exclusive scan via wave shuffles: offs[0]=0, offs[i+1]=sum(deg[0..i]). One block, 256 thr.
__global__ void scan_kernel(const int* __restrict__ deg, int* __restrict__ offs, int N){
  __shared__ int wsum[4];
  int t = threadIdx.x, lane = t & 63, w = t >> 6;
  int carry = 0;
  for(int base = 0; base < N; base += 256){
    int v = (base + t < N) ? deg[base + t] : 0;
    int s = v;
#pragma unroll
    for(int o = 1; o < 64; o <<= 1){
      int u = __shfl_up(s, o);
      if(lane >= o) s += u;
    }
    if(lane == 63) wsum[w] = s;
    __syncthreads();
    int woff = 0;
    for(int i = 0; i < w; ++i) woff += wsum[i];
    if(base + t < N) offs[base + t + 1] = carry + woff + s;
    int tot = wsum[0] + wsum[1] + wsum[2] + wsum[3];
    __syncthreads();
    carry += tot;
  }
  if(t == 0) offs[0] = 0;
}

__global__ void scatter_kernel(const int* __restrict__ dst, int E,
                               const int* __restrict__ offs, int* __restrict__ cursor,
                               int* __restrict__ eids){
  int e = blockIdx.x*blockDim.x + threadIdx.x;
  if(e < E){
    int d = dst[e];
    int pos = offs[d] + atomicAdd(&cursor[d], 1);
    eids[pos] = e;
  }
}

// ---------------- weight transpose + bf16 hi/lo split ----------------
// W[K][N] fp32 -> Th[N][K], Tl[N][K] bf16. block (32,8), tile 32x32.

__global__ void transpose_split_kernel(const float* __restrict__ W,
                                       bf16_t* __restrict__ Th, bf16_t* __restrict__ Tl,
                                       int K, int N){
  __shared__ float t[32][33];
  int k0 = blockIdx.x * 32, n0 = blockIdx.y * 32;
  int tx = threadIdx.x, ty = threadIdx.y;
#pragma unroll
  for(int i = 0; i < 4; ++i)
    t[ty*4 + i][tx] = W[(size_t)(k0 + ty*4 + i) * N + n0 + tx];
  __syncthreads();
#pragma unroll
  for(int i = 0; i < 4; ++i){
    int n = ty*4 + i;
    float v = t[tx][n];                 // = W[k0+tx][n0+n]
    bf16_t h = (bf16_t)v;
    bf16_t l = (bf16_t)(v - (float)h);
    Th[(size_t)(n0 + n) * K + k0 + tx] = h;
    Tl[(size_t)(n0 + n) * K + k0 + tx] = l;
  }
}

// ---------------- MFMA split-bf16 GEMM ----------------
// C[M][N] = A[M][K] (fp32, opt. relu) @ Bt^T  where Bt_hi/lo are [N][K] bf16.
// acc = Ah*Bh + Ah*Bl + Al*Bh  (fp32-class accuracy).
// 256 threads = 4 waves (2x2), tile 128x128, BK=32, mfma_f32_16x16x32_bf16.

template<bool RELU_A, bool HAS_BIAS>
__global__ __launch_bounds__(256) void gemm_mfma_kernel(
    const float* __restrict__ A,
    const bf16_t* __restrict__ Bt_hi, const bf16_t* __restrict__ Bt_lo,
    const float* __restrict__ bias, float* __restrict__ C,
    int M, int N, int K){
  constexpr int LDK = 40;  // 32 + 8 pad elems -> 80B row stride (bank-friendly)
  __shared__ bf16_t Ah[128 * LDK];
  __shared__ bf16_t Al[128 * LDK];
  __shared__ bf16_t Bh[128 * LDK];
  __shared__ bf16_t Bl[128 * LDK];

  const int tid  = threadIdx.x;
  const int lane = tid & 63;
  const int wid  = tid >> 6;
  const int wm = wid >> 1, wn = wid & 1;
  const int row0 = blockIdx.y * 128, col0 = blockIdx.x * 128;
  const int l15 = lane & 15;
  const int kb  = (lane >> 4) * 8;

  f32x4 acc[4][4];
#pragma unroll
  for(int m = 0; m < 4; ++m)
#pragma unroll
    for(int n = 0; n < 4; ++n) acc[m][n] = (f32x4){0.f, 0.f, 0.f, 0.f};

  for(int k0 = 0; k0 < K; k0 += 32){
    __syncthreads();
    // stage A (fp32 -> hi/lo bf16): 128 rows x 32 k = 1024 float4, 4/thread
#pragma unroll
    for(int i = 0; i < 4; ++i){
      int f = tid + i * 256;
      int r = f >> 3, kq = f & 7;
      float4 v = make_float4(0.f, 0.f, 0.f, 0.f);
      if(row0 + r < M) v = *(const float4*)(A + (size_t)(row0 + r) * K + k0 + kq * 4);
      if(RELU_A){ v.x = fmaxf(v.x, 0.f); v.y = fmaxf(v.y, 0.f); v.z = fmaxf(v.z, 0.f); v.w = fmaxf(v.w, 0.f); }
      bf16_t h0 = (bf16_t)v.x, h1 = (bf16_t)v.y, h2 = (bf16_t)v.z, h3 = (bf16_t)v.w;
      bf16x4 hv = (bf16x4){h0, h1, h2, h3};
      bf16x4 lv = (bf16x4){(bf16_t)(v.x - (float)h0), (bf16_t)(v.y - (float)h1),
                           (bf16_t)(v.z - (float)h2), (bf16_t)(v.w - (float)h3)};
      *(bf16x4*)&Ah[r * LDK + kq * 4] = hv;
      *(bf16x4*)&Al[r * LDK + kq * 4] = lv;
    }
    // stage B (pre-split bf16): 128 cols x 32 k = 512 x 16B, 2/thread per array
#pragma unroll
    for(int i = 0; i < 2; ++i){
      int f = tid + i * 256;
      int n = f >> 2, kq = f & 3;
      *(bf16x8*)&Bh[n * LDK + kq * 8] = *(const bf16x8*)(Bt_hi + (size_t)(col0 + n) * K + k0 + kq * 8);
      *(bf16x8*)&Bl[n * LDK + kq * 8] = *(const bf16x8*)(Bt_lo + (size_t)(col0 + n) * K + k0 + kq * 8);
    }
    __syncthreads();

    bf16x8 ah[4], al[4], bh[4], bl[4];
#pragma unroll
    for(int m = 0; m < 4; ++m){
      int r = wm * 64 + m * 16 + l15;
      ah[m] = *(bf16x8*)&Ah[r * LDK + kb];
      al[m] = *(bf16x8*)&Al[r * LDK + kb];
    }
#pragma unroll
    for(int n = 0; n < 4; ++n){
      int c = wn * 64 + n * 16 + l15;
      bh[n] = *(bf16x8*)&Bh[c * LDK + kb];
      bl[n] = *(bf16x8*)&Bl[c * LDK + kb];
    }
#pragma unroll
    for(int m = 0; m < 4; ++m)
#pragma unroll
      for(int n = 0; n < 4; ++n){
        acc[m][n] = __builtin_amdgcn_mfma_f32_16x16x32_bf16(ah[m], bh[n], acc[m][n], 0, 0, 0);
        acc[m][n] = __builtin_amdgcn_mfma_f32_16x16x32_bf16(ah[m], bl[n], acc[m][n], 0, 0, 0);
        acc[m][n] = __builtin_amdgcn_mfma_f32_16x16x32_bf16(al[m], bh[n], acc[m][n], 0, 0, 0);
      }
  }

  // epilogue: D row = (lane>>4)*4 + reg, col = lane&15  [verified layout]
#pragma unroll
  for(int n = 0; n < 4; ++n){
    int col = col0 + wn * 64 + n * 16 + l15;
    float bv = HAS_BIAS ? bias[col] : 0.f;
#pragma unroll
    for(int m = 0; m < 4; ++m){
      int rbase = row0 + wm * 64 + m * 16 + (lane >> 4) * 4;
#pragma unroll
      for(int r = 0; r < 4; ++r){
        if(rbase + r < M) C[(size_t)(rbase + r) * N + col] = acc[m][n][r] + bv;
      }
    }
  }
}

// ---------------- edge alpha: one wave per edge ----------------

__global__ void edge_alpha_kernel(const float* __restrict__ xl, const float* __restrict__ xr,
                                  const float* __restrict__ rproj,
                                  const int* __restrict__ src, const int* __restrict__ dst,
                                  const int* __restrict__ rel,
                                  const float* __restrict__ att,
                                  float* __restrict__ alphaE, int E){
  int w = (int)((blockIdx.x * blockDim.x + threadIdx.x) >> 6);
  int lane = threadIdx.x & 63;
  if(w >= E) return;
  int s = src[w], d = dst[w], r = rel[w];
  const float4* xls = (const float4*)(xl + (size_t)s * 1024);
  const float4* xrd = (const float4*)(xr + (size_t)d * 1024);
  const float4* rp  = (const float4*)(rproj + (size_t)r * 1024);
  const float4* at4 = (const float4*)att;
  float res[4];
#pragma unroll
  for(int j = 0; j < 4; ++j){
    int idx = j * 64 + lane;
    int h = idx >> 5;
    float4 a = xls[idx], b = xrd[idx], c = rp[idx];
    float4 m = make_float4(leaky(a.x + b.x + c.x), leaky(a.y + b.y + c.y),
                           leaky(a.z + b.z + c.z), leaky(a.w + b.w + c.w));
    float4 av = at4[h * 32 + (lane & 31)];
    res[j] = m.x * av.x + m.y * av.y + m.z * av.z + m.w * av.w;
  }
#pragma unroll
  for(int o = 16; o >= 1; o >>= 1){
#pragma unroll
    for(int j = 0; j < 4; ++j) res[j] += __shfl_xor(res[j], o);
  }
  if((lane & 31) == 0){
    int hi = lane >> 5;
#pragma unroll
    for(int j = 0; j < 4; ++j) alphaE[(size_t)w * 8 + 2 * j + hi] = res[j];
  }
}

// ---------------- fused node kernel: one wave per node ----------------

__global__ void node_fused_kernel(const float* __restrict__ xl, const float* __restrict__ xr,
                                  const float* __restrict__ rproj,
                                  const int* __restrict__ offs, const int* __restrict__ eids,
                                  const int* __restrict__ src, const int* __restrict__ rel,
                                  const float* __restrict__ alphaE,
                                  const float* __restrict__ att, const float* __restrict__ bias,
                                  float* __restrict__ xout, int N){
  int node = (int)((blockIdx.x * blockDim.x + threadIdx.x) >> 6);
  int lane = threadIdx.x & 63;
  if(node >= N) return;
  int beg = offs[node], end = offs[node + 1];
  float inv = 1.0f / fmaxf((float)(end - beg), 1.0f);
  const float4* xln = (const float4*)(xl + (size_t)node * 1024);
  const float4* xrn = (const float4*)(xr + (size_t)node * 1024);
  const float4* at4 = (const float4*)att;
  int hbase = lane >> 5;

  float4 lacc[4]; float amax[4];
#pragma unroll
  for(int j = 0; j < 4; ++j){ lacc[j] = make_float4(0.f,0.f,0.f,0.f); amax[j] = -INFINITY; }

  for(int p = beg; p < end; ++p){
    int e = eids[p];
    int r = rel[e];
    const float4* rp = (const float4*)(rproj + (size_t)r * 1024);
#pragma unroll
    for(int j = 0; j < 4; ++j){
      float4 v = rp[j * 64 + lane];
      lacc[j].x += v.x; lacc[j].y += v.y; lacc[j].z += v.z; lacc[j].w += v.w;
      amax[j] = fmaxf(amax[j], alphaE[(size_t)e * 8 + 2 * j + hbase]);
    }
  }

  float4 xl4[4];
  float aself[4];
#pragma unroll
  for(int j = 0; j < 4; ++j){
    int idx = j * 64 + lane;
    xl4[j] = xln[idx];
    float4 xr4 = xrn[idx];
    float4 m = make_float4(leaky(xl4[j].x + xr4.x + lacc[j].x * inv),
                           leaky(xl4[j].y + xr4.y + lacc[j].y * inv),
                           leaky(xl4[j].z + xr4.z + lacc[j].z * inv),
                           leaky(xl4[j].w + xr4.w + lacc[j].w * inv));
    float4 av = at4[(2 * j + hbase) * 32 + (lane & 31)];
    aself[j] = m.x * av.x + m.y * av.y + m.z * av.z + m.w * av.w;
  }
#pragma unroll
  for(int o = 16; o >= 1; o >>= 1){
#pragma unroll
    for(int j = 0; j < 4; ++j) aself[j] += __shfl_xor(aself[j], o);
  }

  float denom[4]; float4 num[4];
#pragma unroll
  for(int j = 0; j < 4; ++j){
    amax[j] = fmaxf(amax[j], aself[j]);
    float ws = expf(aself[j] - amax[j]);
    denom[j] = ws;
    num[j] = make_float4(xl4[j].x * ws, xl4[j].y * ws, xl4[j].z * ws, xl4[j].w * ws);
  }

  for(int p = beg; p < end; ++p){
    int e = eids[p];
    int s = src[e];
    const float4* xs = (const float4*)(xl + (size_t)s * 1024);
#pragma unroll
    for(int j = 0; j < 4; ++j){
      float w = expf(alphaE[(size_t)e * 8 + 2 * j + hbase] - amax[j]);
      denom[j] += w;
      float4 v = xs[j * 64 + lane];
      num[j].x += v.x * w; num[j].y += v.y * w; num[j].z += v.z * w; num[j].w += v.w * w;
    }
  }

  float4 sum = make_float4(0.f,0.f,0.f,0.f);
#pragma unroll
  for(int j = 0; j < 4; ++j){
    float dinv = 1.0f / denom[j];
    sum.x += num[j].x * dinv; sum.y += num[j].y * dinv;
    sum.z += num[j].z * dinv; sum.w += num[j].w * dinv;
  }
  sum.x += __shfl_xor(sum.x, 32);
  sum.y += __shfl_xor(sum.y, 32);
  sum.z += __shfl_xor(sum.z, 32);
  sum.w += __shfl_xor(sum.w, 32);

  if(lane < 32){
    float4 b4 = ((const float4*)bias)[lane];
    float4 o = make_float4(sum.x * 0.125f + b4.x, sum.y * 0.125f + b4.y,
                           sum.z * 0.125f + b4.z, sum.w * 0.125f + b4.w);
    ((float4*)(xout + (size_t)node * 128))[lane] = o;
  }
}

// ---------------- launch ----------------

extern "C" void kernel_launch(void* const* d_in, const int* in_sizes, int n_in,
                              void* d_out, int out_size, void* d_ws, size_t ws_size,
                              hipStream_t stream){
  const float* x0   = (const float*)d_in[0];
  const int*   ei   = (const int*)d_in[1];
  const float* rel0 = (const float*)d_in[2];
  const int*   ridx = (const int*)d_in[3];
  const float* Wl   = (const float*)d_in[4];
  const float* bl   = (const float*)d_in[5];
  const float* Wr   = (const float*)d_in[6];
  const float* br   = (const float*)d_in[7];
  const float* We   = (const float*)d_in[8];
  const float* att  = (const float*)d_in[9];
  const float* bias = (const float*)d_in[10];
  const float* Wb   = (const float*)d_in[11];
  const float* bb   = (const float*)d_in[12];

  const int D = 128, HC = 1024;
  const int N = in_sizes[0] / D;
  const int E = in_sizes[1] / 2;
  const int R = in_sizes[2] / D;
  const int WSZ = D * HC;  // 131072 elems per weight matrix per layer

  const int* src = ei;
  const int* dst = ei + E;

  char* ws = (char*)d_ws;
  size_t off = 0;
  auto alloc = [&](size_t bytes) -> void* {
    void* p = ws + off;
    off += (bytes + 255) & ~(size_t)255;
    return p;
  };
  float* xl     = (float*)alloc((size_t)N * HC * 4);
  float* xr     = (float*)alloc((size_t)N * HC * 4);
  float* rproj  = (float*)alloc((size_t)R * HC * 4);
  float* alphaE = (float*)alloc((size_t)E * 8 * 4);
  float* xbufA  = (float*)alloc((size_t)N * D * 4);
  float* xbufB  = (float*)alloc((size_t)N * D * 4);
  float* rbufA  = (float*)alloc((size_t)R * D * 4);
  float* rbufB  = (float*)alloc((size_t)R * D * 4);
  int* deg    = (int*)alloc((size_t)N * 4);
  int* offs   = (int*)alloc((size_t)(N + 1) * 4);
  int* cursor = (int*)alloc((size_t)N * 4);
  int* eids   = (int*)alloc((size_t)E * 4);
  // transposed + split weights: [layer][N][K] bf16, hi+lo
  bf16_t* tWl_h = (bf16_t*)alloc((size_t)N_LAYERS * WSZ * 2);
  bf16_t* tWl_l = (bf16_t*)alloc((size_t)N_LAYERS * WSZ * 2);
  bf16_t* tWr_h = (bf16_t*)alloc((size_t)N_LAYERS * WSZ * 2);
  bf16_t* tWr_l = (bf16_t*)alloc((size_t)N_LAYERS * WSZ * 2);
  bf16_t* tWe_h = (bf16_t*)alloc((size_t)N_LAYERS * WSZ * 2);
  bf16_t* tWe_l = (bf16_t*)alloc((size_t)N_LAYERS * WSZ * 2);
  bf16_t* tWb_h = (bf16_t*)alloc((size_t)N_LAYERS * WSZ * 2);
  bf16_t* tWb_l = (bf16_t*)alloc((size_t)N_LAYERS * WSZ * 2);
  float* xbuf[2] = {xbufA, xbufB};
  float* rbuf[2] = {rbufA, rbufB};

  float* out_x = (float*)d_out;
  float* out_r = (float*)d_out + (size_t)N * D;

  // CSR build (once; edge structure is layer-invariant)
  fill_int_kernel<<<(N + 255) / 256, 256, 0, stream>>>(deg, 0, N);
  fill_int_kernel<<<(N + 255) / 256, 256, 0, stream>>>(cursor, 0, N);
  hist_kernel<<<(E + 255) / 256, 256, 0, stream>>>(dst, E, deg);
  scan_kernel<<<1, 256, 0, stream>>>(deg, offs, N);
  scatter_kernel<<<(E + 255) / 256, 256, 0, stream>>>(dst, E, offs, cursor, eids);

  // weight prep: transpose + hi/lo split (all layers, upfront)
  dim3 tblk(32, 8);
  for(int l = 0; l < N_LAYERS; ++l){
    size_t wo = (size_t)l * WSZ;
    transpose_split_kernel<<<dim3(D/32, HC/32), tblk, 0, stream>>>(Wl + wo, tWl_h + wo, tWl_l + wo, D, HC);
    transpose_split_kernel<<<dim3(D/32, HC/32), tblk, 0, stream>>>(Wr + wo, tWr_h + wo, tWr_l + wo, D, HC);
    transpose_split_kernel<<<dim3(D/32, HC/32), tblk, 0, stream>>>(We + wo, tWe_h + wo, tWe_l + wo, D, HC);
    transpose_split_kernel<<<dim3(HC/32, D/32), tblk, 0, stream>>>(Wb + wo, tWb_h + wo, tWb_l + wo, HC, D);
  }

  for(int l = 0; l < N_LAYERS; ++l){
    const float* xin = (l == 0) ? x0   : xbuf[(l + 1) & 1];
    float*       xo  = (l == N_LAYERS - 1) ? out_x : xbuf[l & 1];
    const float* rin = (l == 0) ? rel0 : rbuf[(l + 1) & 1];
    float*       ro  = (l == N_LAYERS - 1) ? out_r : rbuf[l & 1];
    size_t wo = (size_t)l * WSZ;
    const float* bl_l  = bl + (size_t)l * HC;
    const float* br_l  = br + (size_t)l * HC;
    const float* att_l = att + (size_t)l * 8 * 128;
    const float* bias_l= bias + (size_t)l * D;
    const float* bb_l  = bb + (size_t)l * D;

    // rproj = relations @ We (no bias)
    gemm_mfma_kernel<false,false><<<dim3(HC/128, (R+127)/128), 256, 0, stream>>>(
        rin, tWe_h + wo, tWe_l + wo, nullptr, rproj, R, HC, D);
    // xl = x @ Wl + bl ; xr = x @ Wr + br
    gemm_mfma_kernel<false,true><<<dim3(HC/128, (N+127)/128), 256, 0, stream>>>(
        xin, tWl_h + wo, tWl_l + wo, bl_l, xl, N, HC, D);
    gemm_mfma_kernel<false,true><<<dim3(HC/128, (N+127)/128), 256, 0, stream>>>(
        xin, tWr_h + wo, tWr_l + wo, br_l, xr, N, HC, D);
    // per-edge attention logits
    edge_alpha_kernel<<<(E * 64 + 255) / 256, 256, 0, stream>>>(
        xl, xr, rproj, src, dst, ridx, att_l, alphaE, E);
    // fused node pass: self-loop mean, softmax, aggregate, head-mean + bias
    node_fused_kernel<<<(N * 64 + 255) / 256, 256, 0, stream>>>(
        xl, xr, rproj, offs, eids, src, ridx, alphaE, att_l, bias_l, xo, N);
    // relation update: relu(rproj) @ Wb + bb
    gemm_mfma_kernel<true,true><<<dim3(D/128, (R+127)/128), 256, 0, stream>>>(
        rproj, tWb_h + wo, tWb_l + wo, bb_l, ro, R, D, HC);
  }
}

// Round 3
// 744.340 us; speedup vs baseline: 1.6191x; 1.5516x over previous
//
#include <hip/hip_runtime.h>
#include <hip/hip_bf16.h>
#include <math.h>

#define NEG_SLOPE 0.2f
#define N_LAYERS 4

typedef __bf16 bf16_t;
typedef __attribute__((ext_vector_type(8))) __bf16 bf16x8;
typedef __attribute__((ext_vector_type(4))) __bf16 bf16x4;
typedef __attribute__((ext_vector_type(4))) float f32x4;

static __device__ __forceinline__ float leaky(float v){ return v > 0.f ? v : NEG_SLOPE * v; }

// ---------------- CSR build (edge structure fixed across layers) ----------------

__global__ void fill_int_kernel(int* __restrict__ p, int v, int n){
  int i = blockIdx.x*blockDim.x + threadIdx.x;
  if(i < n) p[i] = v;
}

__global__ void fill_bias_kernel(float* __restrict__ out, const float* __restrict__ b, int rows){
  int i = blockIdx.x*blockDim.x + threadIdx.x;
  if(i < rows * 128) out[i] = b[i & 127];
}

__global__ void hist_kernel(const int* __restrict__ dst, int E, int* __restrict__ deg){
  int e = blockIdx.x*blockDim.x + threadIdx.x;
  if(e < E) atomicAdd(&deg[dst[e]], 1);
}

// exclusive scan via wave shuffles: offs[0]=0, offs[i+1]=sum(deg[0..i]). One block, 256 thr.
__global__ void scan_kernel(const int* __restrict__ deg, int* __restrict__ offs, int N){
  __shared__ int wsum[4];
  int t = threadIdx.x, lane = t & 63, w = t >> 6;
  int carry = 0;
  for(int base = 0; base < N; base += 256){
    int v = (base + t < N) ? deg[base + t] : 0;
    int s = v;
#pragma unroll
    for(int o = 1; o < 64; o <<= 1){
      int u = __shfl_up(s, o);
      if(lane >= o) s += u;
    }
    if(lane == 63) wsum[w] = s;
    __syncthreads();
    int woff = 0;
    for(int i = 0; i < w; ++i) woff += wsum[i];
    if(base + t < N) offs[base + t + 1] = carry + woff + s;
    int tot = wsum[0] + wsum[1] + wsum[2] + wsum[3];
    __syncthreads();
    carry += tot;
  }
  if(t == 0) offs[0] = 0;
}

__global__ void scatter_kernel(const int* __restrict__ dst, int E,
                               const int* __restrict__ offs, int* __restrict__ cursor,
                               int* __restrict__ eids){
  int e = blockIdx.x*blockDim.x + threadIdx.x;
  if(e < E){
    int d = dst[e];
    int pos = offs[d] + atomicAdd(&cursor[d], 1);
    eids[pos] = e;
  }
}

// ---------------- weight transpose + bf16 hi/lo split ----------------

__global__ void transpose_split_kernel(const float* __restrict__ W,
                                       bf16_t* __restrict__ Th, bf16_t* __restrict__ Tl,
                                       int K, int N){
  __shared__ float t[32][33];
  int k0 = blockIdx.x * 32, n0 = blockIdx.y * 32;
  int tx = threadIdx.x, ty = threadIdx.y;
#pragma unroll
  for(int i = 0; i < 4; ++i)
    t[ty*4 + i][tx] = W[(size_t)(k0 + ty*4 + i) * N + n0 + tx];
  __syncthreads();
#pragma unroll
  for(int i = 0; i < 4; ++i){
    int n = ty*4 + i;
    float v = t[tx][n];
    bf16_t h = (bf16_t)v;
    bf16_t l = (bf16_t)(v - (float)h);
    Th[(size_t)(n0 + n) * K + k0 + tx] = h;
    Tl[(size_t)(n0 + n) * K + k0 + tx] = l;
  }
}

// ---------------- MFMA split-bf16 GEMM ----------------
// C[M][N] = A[M][K] (fp32, opt. relu) @ Bt^T, Bt hi/lo [N][K] bf16.
// acc = Ah*Bh + Ah*Bl + Al*Bh. 4 waves, tile 128x128, BK=32.
// SPLITK: blockIdx.z selects a 128-wide K slice; epilogue atomicAdds (C pre-filled with bias).

template<bool RELU_A, bool HAS_BIAS, bool WRITE_BF16, bool SPLITK>
__global__ __launch_bounds__(256) void gemm_mfma_kernel(
    const float* __restrict__ A,
    const bf16_t* __restrict__ Bt_hi, const bf16_t* __restrict__ Bt_lo,
    const float* __restrict__ bias, float* __restrict__ C, bf16_t* __restrict__ Cb,
    int M, int N, int K){
  constexpr int LDK = 40;
  __shared__ bf16_t Ah[128 * LDK];
  __shared__ bf16_t Al[128 * LDK];
  __shared__ bf16_t Bh[128 * LDK];
  __shared__ bf16_t Bl[128 * LDK];

  const int tid  = threadIdx.x;
  const int lane = tid & 63;
  const int wid  = tid >> 6;
  const int wm = wid >> 1, wn = wid & 1;
  const int row0 = blockIdx.y * 128, col0 = blockIdx.x * 128;
  const int l15 = lane & 15;
  const int kb  = (lane >> 4) * 8;

  f32x4 acc[4][4];
#pragma unroll
  for(int m = 0; m < 4; ++m)
#pragma unroll
    for(int n = 0; n < 4; ++n) acc[m][n] = (f32x4){0.f, 0.f, 0.f, 0.f};

  int kbeg = 0, kend = K;
  if(SPLITK){ kbeg = blockIdx.z * 128; kend = kbeg + 128; }

  for(int k0 = kbeg; k0 < kend; k0 += 32){
    __syncthreads();
#pragma unroll
    for(int i = 0; i < 4; ++i){
      int f = tid + i * 256;
      int r = f >> 3, kq = f & 7;
      float4 v = make_float4(0.f, 0.f, 0.f, 0.f);
      if(row0 + r < M) v = *(const float4*)(A + (size_t)(row0 + r) * K + k0 + kq * 4);
      if(RELU_A){ v.x = fmaxf(v.x, 0.f); v.y = fmaxf(v.y, 0.f); v.z = fmaxf(v.z, 0.f); v.w = fmaxf(v.w, 0.f); }
      bf16_t h0 = (bf16_t)v.x, h1 = (bf16_t)v.y, h2 = (bf16_t)v.z, h3 = (bf16_t)v.w;
      bf16x4 hv = (bf16x4){h0, h1, h2, h3};
      bf16x4 lv = (bf16x4){(bf16_t)(v.x - (float)h0), (bf16_t)(v.y - (float)h1),
                           (bf16_t)(v.z - (float)h2), (bf16_t)(v.w - (float)h3)};
      *(bf16x4*)&Ah[r * LDK + kq * 4] = hv;
      *(bf16x4*)&Al[r * LDK + kq * 4] = lv;
    }
#pragma unroll
    for(int i = 0; i < 2; ++i){
      int f = tid + i * 256;
      int n = f >> 2, kq = f & 3;
      *(bf16x8*)&Bh[n * LDK + kq * 8] = *(const bf16x8*)(Bt_hi + (size_t)(col0 + n) * K + k0 + kq * 8);
      *(bf16x8*)&Bl[n * LDK + kq * 8] = *(const bf16x8*)(Bt_lo + (size_t)(col0 + n) * K + k0 + kq * 8);
    }
    __syncthreads();

    bf16x8 ah[4], al[4], bh[4], bl[4];
#pragma unroll
    for(int m = 0; m < 4; ++m){
      int r = wm * 64 + m * 16 + l15;
      ah[m] = *(bf16x8*)&Ah[r * LDK + kb];
      al[m] = *(bf16x8*)&Al[r * LDK + kb];
    }
#pragma unroll
    for(int n = 0; n < 4; ++n){
      int c = wn * 64 + n * 16 + l15;
      bh[n] = *(bf16x8*)&Bh[c * LDK + kb];
      bl[n] = *(bf16x8*)&Bl[c * LDK + kb];
    }
#pragma unroll
    for(int m = 0; m < 4; ++m)
#pragma unroll
      for(int n = 0; n < 4; ++n){
        acc[m][n] = __builtin_amdgcn_mfma_f32_16x16x32_bf16(ah[m], bh[n], acc[m][n], 0, 0, 0);
        acc[m][n] = __builtin_amdgcn_mfma_f32_16x16x32_bf16(ah[m], bl[n], acc[m][n], 0, 0, 0);
        acc[m][n] = __builtin_amdgcn_mfma_f32_16x16x32_bf16(al[m], bh[n], acc[m][n], 0, 0, 0);
      }
  }

  // D layout: row = (lane>>4)*4 + reg, col = lane&15
#pragma unroll
  for(int n = 0; n < 4; ++n){
    int col = col0 + wn * 64 + n * 16 + l15;
    float bv = HAS_BIAS ? bias[col] : 0.f;
#pragma unroll
    for(int m = 0; m < 4; ++m){
      int rbase = row0 + wm * 64 + m * 16 + (lane >> 4) * 4;
#pragma unroll
      for(int r = 0; r < 4; ++r){
        if(rbase + r < M){
          size_t idx = (size_t)(rbase + r) * N + col;
          if(SPLITK){
            atomicAdd(&C[idx], acc[m][n][r]);
          } else {
            float val = acc[m][n][r] + bv;
            C[idx] = val;
            if(WRITE_BF16) Cb[idx] = (bf16_t)val;
          }
        }
      }
    }
  }
}

// ---------------- fused node kernel: one wave per node ----------------
// pass1 (per incoming edge): alpha logit from bf16 xl[src]/rproj[rel] + own fp32 xr row;
//        accumulate rproj sum (self-loop mean) + running max; stash logits to alphaE.
// then self alpha, softmax, pass2: exact fp32 weighted xl[src] sum, head-mean + bias.

__global__ void node_fused_kernel(const float* __restrict__ xl, const float* __restrict__ xr,
                                  const bf16_t* __restrict__ xlb, const bf16_t* __restrict__ rpb,
                                  const int* __restrict__ offs, const int* __restrict__ eids,
                                  const int* __restrict__ src, const int* __restrict__ rel,
                                  const float* __restrict__ att, const float* __restrict__ bias,
                                  float* __restrict__ alphaE, float* __restrict__ xout, int N){
  int node = (int)((blockIdx.x * blockDim.x + threadIdx.x) >> 6);
  int lane = threadIdx.x & 63;
  if(node >= N) return;
  int beg = offs[node], end = offs[node + 1];
  float inv = 1.0f / fmaxf((float)(end - beg), 1.0f);
  const float4* xln = (const float4*)(xl + (size_t)node * 1024);
  const float4* xrn = (const float4*)(xr + (size_t)node * 1024);
  const float4* at4 = (const float4*)att;
  const int hbase = lane >> 5;
  const int l31 = lane & 31;

  float4 av[4], xr4[4], xl4[4];
  f32x4 lacc[4];
  float amax[4];
#pragma unroll
  for(int j = 0; j < 4; ++j){
    av[j]  = at4[(2 * j + hbase) * 32 + l31];
    xr4[j] = xrn[j * 64 + lane];
    xl4[j] = xln[j * 64 + lane];
    lacc[j] = (f32x4){0.f, 0.f, 0.f, 0.f};
    amax[j] = -INFINITY;
  }

  // pass 1: alpha logits + rproj accumulation
  for(int p = beg; p < end; ++p){
    int e = eids[p];
    int s = src[e];
    int r = rel[e];
    const bf16_t* xs = xlb + (size_t)s * 1024;
    const bf16_t* rp = rpb + (size_t)r * 1024;
    float res[4];
#pragma unroll
    for(int j = 0; j < 4; ++j){
      int e4 = 4 * (j * 64 + lane);
      bf16x4 a = *(const bf16x4*)(xs + e4);
      bf16x4 b = *(const bf16x4*)(rp + e4);
      float r0 = (float)b[0], r1 = (float)b[1], r2 = (float)b[2], r3 = (float)b[3];
      lacc[j][0] += r0; lacc[j][1] += r1; lacc[j][2] += r2; lacc[j][3] += r3;
      float m0 = leaky((float)a[0] + xr4[j].x + r0);
      float m1 = leaky((float)a[1] + xr4[j].y + r1);
      float m2 = leaky((float)a[2] + xr4[j].z + r2);
      float m3 = leaky((float)a[3] + xr4[j].w + r3);
      res[j] = m0 * av[j].x + m1 * av[j].y + m2 * av[j].z + m3 * av[j].w;
    }
#pragma unroll
    for(int o = 16; o >= 1; o >>= 1){
#pragma unroll
      for(int j = 0; j < 4; ++j) res[j] += __shfl_xor(res[j], o);
    }
#pragma unroll
    for(int j = 0; j < 4; ++j){
      amax[j] = fmaxf(amax[j], res[j]);
      if(l31 == 0) alphaE[(size_t)e * 8 + 2 * j + hbase] = res[j];
    }
  }

  // self-loop alpha
  float aself[4];
#pragma unroll
  for(int j = 0; j < 4; ++j){
    float m0 = leaky(xl4[j].x + xr4[j].x + lacc[j][0] * inv);
    float m1 = leaky(xl4[j].y + xr4[j].y + lacc[j][1] * inv);
    float m2 = leaky(xl4[j].z + xr4[j].z + lacc[j][2] * inv);
    float m3 = leaky(xl4[j].w + xr4[j].w + lacc[j][3] * inv);
    aself[j] = m0 * av[j].x + m1 * av[j].y + m2 * av[j].z + m3 * av[j].w;
  }
#pragma unroll
  for(int o = 16; o >= 1; o >>= 1){
#pragma unroll
    for(int j = 0; j < 4; ++j) aself[j] += __shfl_xor(aself[j], o);
  }

  float denom[4]; float4 num[4];
#pragma unroll
  for(int j = 0; j < 4; ++j){
    amax[j] = fmaxf(amax[j], aself[j]);
    float ws = expf(aself[j] - amax[j]);
    denom[j] = ws;
    num[j] = make_float4(xl4[j].x * ws, xl4[j].y * ws, xl4[j].z * ws, xl4[j].w * ws);
  }

  // pass 2: exact fp32 weighted message sum
  for(int p = beg; p < end; ++p){
    int e = eids[p];
    int s = src[e];
    const float4* xs = (const float4*)(xl + (size_t)s * 1024);
#pragma unroll
    for(int j = 0; j < 4; ++j){
      float w = expf(alphaE[(size_t)e * 8 + 2 * j + hbase] - amax[j]);
      denom[j] += w;
      float4 v = xs[j * 64 + lane];
      num[j].x += v.x * w; num[j].y += v.y * w; num[j].z += v.z * w; num[j].w += v.w * w;
    }
  }

  float4 sum = make_float4(0.f,0.f,0.f,0.f);
#pragma unroll
  for(int j = 0; j < 4; ++j){
    float dinv = 1.0f / denom[j];
    sum.x += num[j].x * dinv; sum.y += num[j].y * dinv;
    sum.z += num[j].z * dinv; sum.w += num[j].w * dinv;
  }
  sum.x += __shfl_xor(sum.x, 32);
  sum.y += __shfl_xor(sum.y, 32);
  sum.z += __shfl_xor(sum.z, 32);
  sum.w += __shfl_xor(sum.w, 32);

  if(lane < 32){
    float4 b4 = ((const float4*)bias)[lane];
    float4 o = make_float4(sum.x * 0.125f + b4.x, sum.y * 0.125f + b4.y,
                           sum.z * 0.125f + b4.z, sum.w * 0.125f + b4.w);
    ((float4*)(xout + (size_t)node * 128))[lane] = o;
  }
}

// ---------------- launch ----------------

extern "C" void kernel_launch(void* const* d_in, const int* in_sizes, int n_in,
                              void* d_out, int out_size, void* d_ws, size_t ws_size,
                              hipStream_t stream){
  const float* x0   = (const float*)d_in[0];
  const int*   ei   = (const int*)d_in[1];
  const float* rel0 = (const float*)d_in[2];
  const int*   ridx = (const int*)d_in[3];
  const float* Wl   = (const float*)d_in[4];
  const float* bl   = (const float*)d_in[5];
  const float* Wr   = (const float*)d_in[6];
  const float* br   = (const float*)d_in[7];
  const float* We   = (const float*)d_in[8];
  const float* att  = (const float*)d_in[9];
  const float* bias = (const float*)d_in[10];
  const float* Wb   = (const float*)d_in[11];
  const float* bb   = (const float*)d_in[12];

  const int D = 128, HC = 1024;
  const int N = in_sizes[0] / D;
  const int E = in_sizes[1] / 2;
  const int R = in_sizes[2] / D;
  const int WSZ = D * HC;

  const int* src = ei;
  const int* dst = ei + E;

  char* ws = (char*)d_ws;
  size_t off = 0;
  auto alloc = [&](size_t bytes) -> void* {
    void* p = ws + off;
    off += (bytes + 255) & ~(size_t)255;
    return p;
  };
  float*  xl     = (float*)alloc((size_t)N * HC * 4);
  float*  xr     = (float*)alloc((size_t)N * HC * 4);
  float*  rproj  = (float*)alloc((size_t)R * HC * 4);
  bf16_t* xlb    = (bf16_t*)alloc((size_t)N * HC * 2);
  bf16_t* rpb    = (bf16_t*)alloc((size_t)R * HC * 2);
  float*  alphaE = (float*)alloc((size_t)E * 8 * 4);
  float*  xbufA  = (float*)alloc((size_t)N * D * 4);
  float*  xbufB  = (float*)alloc((size_t)N * D * 4);
  float*  rbufA  = (float*)alloc((size_t)R * D * 4);
  float*  rbufB  = (float*)alloc((size_t)R * D * 4);
  int* deg    = (int*)alloc((size_t)N * 4);
  int* offs   = (int*)alloc((size_t)(N + 1) * 4);
  int* cursor = (int*)alloc((size_t)N * 4);
  int* eids   = (int*)alloc((size_t)E * 4);
  bf16_t* tWl_h = (bf16_t*)alloc((size_t)N_LAYERS * WSZ * 2);
  bf16_t* tWl_l = (bf16_t*)alloc((size_t)N_LAYERS * WSZ * 2);
  bf16_t* tWr_h = (bf16_t*)alloc((size_t)N_LAYERS * WSZ * 2);
  bf16_t* tWr_l = (bf16_t*)alloc((size_t)N_LAYERS * WSZ * 2);
  bf16_t* tWe_h = (bf16_t*)alloc((size_t)N_LAYERS * WSZ * 2);
  bf16_t* tWe_l = (bf16_t*)alloc((size_t)N_LAYERS * WSZ * 2);
  bf16_t* tWb_h = (bf16_t*)alloc((size_t)N_LAYERS * WSZ * 2);
  bf16_t* tWb_l = (bf16_t*)alloc((size_t)N_LAYERS * WSZ * 2);
  float* xbuf[2] = {xbufA, xbufB};
  float* rbuf[2] = {rbufA, rbufB};

  float* out_x = (float*)d_out;
  float* out_r = (float*)d_out + (size_t)N * D;

  // CSR build (once; edge structure is layer-invariant)
  fill_int_kernel<<<(N + 255) / 256, 256, 0, stream>>>(deg, 0, N);
  fill_int_kernel<<<(N + 255) / 256, 256, 0, stream>>>(cursor, 0, N);
  hist_kernel<<<(E + 255) / 256, 256, 0, stream>>>(dst, E, deg);
  scan_kernel<<<1, 256, 0, stream>>>(deg, offs, N);
  scatter_kernel<<<(E + 255) / 256, 256, 0, stream>>>(dst, E, offs, cursor, eids);

  // weight prep: transpose + hi/lo split (all layers, upfront)
  dim3 tblk(32, 8);
  for(int l = 0; l < N_LAYERS; ++l){
    size_t wo = (size_t)l * WSZ;
    transpose_split_kernel<<<dim3(D/32, HC/32), tblk, 0, stream>>>(Wl + wo, tWl_h + wo, tWl_l + wo, D, HC);
    transpose_split_kernel<<<dim3(D/32, HC/32), tblk, 0, stream>>>(Wr + wo, tWr_h + wo, tWr_l + wo, D, HC);
    transpose_split_kernel<<<dim3(D/32, HC/32), tblk, 0, stream>>>(We + wo, tWe_h + wo, tWe_l + wo, D, HC);
    transpose_split_kernel<<<dim3(HC/32, D/32), tblk, 0, stream>>>(Wb + wo, tWb_h + wo, tWb_l + wo, HC, D);
  }

  for(int l = 0; l < N_LAYERS; ++l){
    const float* xin = (l == 0) ? x0   : xbuf[(l + 1) & 1];
    float*       xo  = (l == N_LAYERS - 1) ? out_x : xbuf[l & 1];
    const float* rin = (l == 0) ? rel0 : rbuf[(l + 1) & 1];
    float*       ro  = (l == N_LAYERS - 1) ? out_r : rbuf[l & 1];
    size_t wo = (size_t)l * WSZ;
    const float* bl_l  = bl + (size_t)l * HC;
    const float* br_l  = br + (size_t)l * HC;
    const float* att_l = att + (size_t)l * 8 * 128;
    const float* bias_l= bias + (size_t)l * D;
    const float* bb_l  = bb + (size_t)l * D;

    // rproj = relations @ We (no bias) + bf16 copy
    gemm_mfma_kernel<false,false,true,false><<<dim3(HC/128, (R+127)/128), 256, 0, stream>>>(
        rin, tWe_h + wo, tWe_l + wo, nullptr, rproj, rpb, R, HC, D);
    // xl = x @ Wl + bl (+ bf16 copy) ; xr = x @ Wr + br
    gemm_mfma_kernel<false,true,true,false><<<dim3(HC/128, (N+127)/128), 256, 0, stream>>>(
        xin, tWl_h + wo, tWl_l + wo, bl_l, xl, xlb, N, HC, D);
    gemm_mfma_kernel<false,true,false,false><<<dim3(HC/128, (N+127)/128), 256, 0, stream>>>(
        xin, tWr_h + wo, tWr_l + wo, br_l, xr, nullptr, N, HC, D);
    // fused node pass: alpha logits + self-loop mean + softmax + aggregate + head-mean + bias
    node_fused_kernel<<<(N * 64 + 255) / 256, 256, 0, stream>>>(
        xl, xr, xlb, rpb, offs, eids, src, ridx, att_l, bias_l, alphaE, xo, N);
    // relation update: ro = relu(rproj) @ Wb + bb, split-K over 8 slices
    fill_bias_kernel<<<(R * 128 + 255) / 256, 256, 0, stream>>>(ro, bb_l, R);
    gemm_mfma_kernel<true,false,false,true><<<dim3(D/128, (R+127)/128, 8), 256, 0, stream>>>(
        rproj, tWb_h + wo, tWb_l + wo, nullptr, ro, nullptr, R, D, HC);
  }
}